// Round 9
// baseline (144.727 us; speedup 1.0000x reference)
//
#include <hip/hip_runtime.h>
#include <hip/hip_bf16.h>
#include <math.h>

#define BS 1024
#define D 128
#define NP 100000
#define PROWS 100096              // padded to multiple of 128 (96 zero rows)
#define NPB 782                   // proxy-conversion blocks (128 proxies each)
#define NSLICE 16                 // rowsum slices (atomic contention / 16)
#define LOG2E 1.44269504088896340736f

typedef float f32x4 __attribute__((ext_vector_type(4)));
typedef float f32x16 __attribute__((ext_vector_type(16)));
typedef __bf16 bf16x8 __attribute__((ext_vector_type(8)));
typedef unsigned short u16x8 __attribute__((ext_vector_type(8)));

#if defined(__has_builtin)
#if __has_builtin(__builtin_amdgcn_exp2f)
#define FAST_EXP2(x) __builtin_amdgcn_exp2f(x)
#endif
#endif
#ifndef FAST_EXP2
#define FAST_EXP2(x) exp2f(x)
#endif

static __device__ __forceinline__ unsigned short f2bf(float x) {
    unsigned int u = __float_as_uint(x);
    return (unsigned short)((u + 0x7fffu + ((u >> 16) & 1u)) >> 16);  // RNE
}

// ---------- kernel 1 (combined prep) --------------------------------------
// blocks 0..127   : batch -> bf16 Abat (fragment-ready), d_pos, zero rowsum
// blocks 128..909 : proxies -> bf16 Pfrag (fragment-ready A-operand layout)
// Fragment-ready layout (both matrices, validated rounds 3-8, absmax 0.0):
// element (row,k) at byte
//   ((row>>5)*8 + (k>>4))*1024 + ((k>>3)&1)*512 + (row&31)*16 + (k&7)*2
// so a wave's fragment load for (group, K-step s) is base + s*1024 + lane*16
// -- one fully-coalesced 1KB load per instruction.
__global__ __launch_bounds__(256) void prep_kernel(
    const float* __restrict__ batch, const float* __restrict__ proxies,
    const int* __restrict__ labels, unsigned short* __restrict__ Abat,
    unsigned short* __restrict__ Pfrag,
    float* __restrict__ d_pos, float* __restrict__ rowsum,
    float* __restrict__ out)
{
    if (blockIdx.x < 128) {
        // ---- batch branch (unchanged from rounds 5-8) --------------------
        if (threadIdx.x < 128) rowsum[blockIdx.x * 128 + threadIdx.x] = 0.f;
        if (blockIdx.x == 0 && threadIdx.x == 0) out[0] = 0.f;

        int wave = threadIdx.x >> 6, lane = threadIdx.x & 63;
        int sub = lane >> 5, c = lane & 31;
        int row = blockIdx.x * 8 + wave * 2 + sub;   // 0..1023 (batch col)
        float4 v = *(const float4*)(batch + (size_t)row * D + c * 4);
        float ss = v.x*v.x + v.y*v.y + v.z*v.z + v.w*v.w;
        #pragma unroll
        for (int m = 1; m < 32; m <<= 1) ss += __shfl_xor(ss, m, 64);
        float sc = 3.0f / fmaxf(sqrtf(ss), 1e-12f);
        ushort4 pk;
        pk.x = f2bf(v.x*sc); pk.y = f2bf(v.y*sc);
        pk.z = f2bf(v.z*sc); pk.w = f2bf(v.w*sc);
        {
            int col_blk = row >> 5, lr = row & 31;
            int s = c >> 2, h2 = (c >> 1) & 1, j0 = (c & 1) * 4;
            size_t off = (((size_t)(col_blk * 8 + s) * 2 + h2) << 9) + lr * 16 + j0 * 2;
            *(ushort4*)((char*)Abat + off) = pk;
        }
        int lab = labels[row];
        float4 p4 = *(const float4*)(proxies + (size_t)lab * D + c * 4);
        float ps = p4.x*p4.x + p4.y*p4.y + p4.z*p4.z + p4.w*p4.w;
        #pragma unroll
        for (int m = 1; m < 32; m <<= 1) ps += __shfl_xor(ps, m, 64);
        float psc = 3.0f / fmaxf(sqrtf(ps), 1e-12f);
        float dt = (v.x*sc)*(p4.x*psc) + (v.y*sc)*(p4.y*psc)
                 + (v.z*sc)*(p4.z*psc) + (v.w*sc)*(p4.w*psc);
        #pragma unroll
        for (int m = 1; m < 32; m <<= 1) dt += __shfl_xor(dt, m, 64);
        if (c == 0) d_pos[row] = 18.0f - 2.0f * dt;
    } else {
        // ---- proxy branch: 128 proxies/block -> normalized bf16 Pfrag ----
        int r = threadIdx.x >> 1, q = threadIdx.x & 1;   // proxy-in-block, k-half
        int pidx = (blockIdx.x - 128) * 128 + r;          // 0..100095
        const float* src = proxies + (size_t)pidx * D + q * 64;
        float ss = 0.f;
        if (pidx < NP) {
            #pragma unroll
            for (int j = 0; j < 16; ++j) {
                float4 v = *(const float4*)(src + j * 4);
                ss += v.x*v.x + v.y*v.y + v.z*v.z + v.w*v.w;
            }
        }
        ss += __shfl_xor(ss, 1, 64);             // combine the 2 k-halves
        float sc = 3.0f / fmaxf(sqrtf(ss), 1e-12f);
        #pragma unroll
        for (int i2 = 0; i2 < 8; ++i2) {
            u16x8 w = (u16x8){0,0,0,0,0,0,0,0};
            if (pidx < NP) {
                float4 a = *(const float4*)(src + i2 * 8);
                float4 b = *(const float4*)(src + i2 * 8 + 4);
                w[0] = f2bf(a.x*sc); w[1] = f2bf(a.y*sc);
                w[2] = f2bf(a.z*sc); w[3] = f2bf(a.w*sc);
                w[4] = f2bf(b.x*sc); w[5] = f2bf(b.y*sc);
                w[6] = f2bf(b.z*sc); w[7] = f2bf(b.w*sc);
            }
            int cl = q * 8 + i2;                 // 16B k-chunk index (k=cl*8..)
            size_t off = (((size_t)(pidx >> 5) * 8 + (cl >> 1)) << 10)
                       + ((size_t)(cl & 1) << 9) + (pidx & 31) * 16;
            *(u16x8*)((char*)Pfrag + off) = w;
        }
    }
}

// ---------- kernel 2: pure-streaming GEMM + exp row-sums ------------------
// NO LDS. NO barrier. NO fp32 proxy read. Each wave is independent:
// tile = 64 proxies x 512 batch cols. Af cache (64 proxies x K=128 = 64
// regs) loaded once via 16 coalesced 1KB loads from L3-resident Pfrag;
// then 16 col-blocks of {8 coalesced Bf loads (L2-resident Abat) ->
// 2 interleaved 8-step MFMA chains -> exp epilogue -> one atomic}.
// Rationale: rounds 5-8 proved the stage-LDS paradigm is floor-bound at
// ~53us by the per-block serial staging phase (round 8: duplicating
// staging directly added its cost). Removing the phase removes the floor.
// 3128 uniform waves (782 blocks x 4), 12.2/CU supply vs 16/CU VGPR cap.
// Budget: Af 64 + Bf 32 + acc 32 (AGPR-placed; round-0 precedent) + misc.
// __launch_bounds__ law (rounds 1/2/4/5): reg cap = 256/arg2; arg=2 only.
__global__ __launch_bounds__(256, 2) void main_kernel(
    const unsigned short* __restrict__ Abat,   // batch, fragment-ready
    const unsigned short* __restrict__ Pfrag,  // proxies, fragment-ready
    float* __restrict__ rowsum)                // [NSLICE][BS]
{
    const int tid = threadIdx.x;
    const int lane = tid & 63;
    const int wave = tid >> 6;                 // 0..3
    const int l31 = lane & 31, hi = lane >> 5;
    const int g = blockIdx.x * 4 + wave;       // 0..3127
    const int pg = g >> 1;                     // 64-proxy group, 0..1563
    const int half = g & 1;                    // which 512 batch cols

    // ---- Af cache: 2 groups x 8 K-steps, coalesced 1KB loads -------------
    const char* ap = (const char*)Pfrag + ((size_t)pg << 14) + lane * 16;
    bf16x8 Af[2][8];
    #pragma unroll
    for (int t = 0; t < 2; ++t) {
        #pragma unroll
        for (int s = 0; s < 8; ++s)
            Af[t][s] = *(const bf16x8*)(ap + (size_t)(((t << 3) | s) << 10));
    }

    const float c1 = 2.0f * LOG2E, c0 = -18.0f * LOG2E;
    float* rs_base = rowsum + (size_t)(pg & (NSLICE - 1)) * BS;

    #pragma unroll 1
    for (int cb = half * 16; cb < half * 16 + 16; ++cb) {
        // Bf: 32 cols x K=128, 8 coalesced 1KB loads from L2-resident Abat
        const char* bp = (const char*)Abat + ((size_t)cb << 13) + lane * 16;
        bf16x8 Bf[8];
        #pragma unroll
        for (int s = 0; s < 8; ++s)
            Bf[s] = *(const bf16x8*)(bp + ((size_t)s << 10));

        f32x16 a0 = {0.f,0.f,0.f,0.f,0.f,0.f,0.f,0.f,
                     0.f,0.f,0.f,0.f,0.f,0.f,0.f,0.f};
        f32x16 a1 = a0;
        #pragma unroll
        for (int s = 0; s < 8; ++s) {
            a0 = __builtin_amdgcn_mfma_f32_32x32x16_bf16(Af[0][s], Bf[s], a0, 0, 0, 0);
            a1 = __builtin_amdgcn_mfma_f32_32x32x16_bf16(Af[1][s], Bf[s], a1, 0, 0, 0);
        }
        // epilogue: lane's batch col = cb*32 + l31; 32 proxy rows in-lane
        float e0 = 0.f, e1 = 0.f, e2 = 0.f, e3 = 0.f;
        #pragma unroll
        for (int r = 0; r < 4; ++r) {
            e0 += FAST_EXP2(fmaf(a0[4*r+0], c1, c0));
            e1 += FAST_EXP2(fmaf(a0[4*r+1], c1, c0));
            e2 += FAST_EXP2(fmaf(a0[4*r+2], c1, c0));
            e3 += FAST_EXP2(fmaf(a0[4*r+3], c1, c0));
            e0 += FAST_EXP2(fmaf(a1[4*r+0], c1, c0));
            e1 += FAST_EXP2(fmaf(a1[4*r+1], c1, c0));
            e2 += FAST_EXP2(fmaf(a1[4*r+2], c1, c0));
            e3 += FAST_EXP2(fmaf(a1[4*r+3], c1, c0));
        }
        float rs = (e0 + e1) + (e2 + e3);
        rs += __shfl_xor(rs, 32, 64);            // combine the two row-halves
        if (hi == 0)
            atomicAdd(rs_base + cb * 32 + l31, rs);
    }
}

// ---------- kernel 3: final lse + mean (4 blocks, atomicAdd out) ----------
__global__ __launch_bounds__(256) void final_kernel(
    const float* __restrict__ rowsum, const float* __restrict__ d_pos,
    float* __restrict__ out)
{
    int row = blockIdx.x * 256 + threadIdx.x;
    float tot = 0.f;
    #pragma unroll
    for (int s = 0; s < NSLICE; ++s)
        tot += rowsum[(size_t)s * BS + row];
    float dp = d_pos[row];
    const float PADC = 96.0f * exp2f(-18.0f * LOG2E);  // zero-pad rows
    float neg = tot - expf(-dp) - PADC;                // drop own column
    float val = dp + logf(fmaxf(neg, 1e-37f));
    #pragma unroll
    for (int m = 1; m < 64; m <<= 1) val += __shfl_xor(val, m, 64);
    __shared__ float red[4];
    if ((threadIdx.x & 63) == 0) red[threadIdx.x >> 6] = val;
    __syncthreads();
    if (threadIdx.x == 0) {
        float v = (red[0] + red[1]) + (red[2] + red[3]);
        atomicAdd(out, v * (1.0f / 1024.0f));
    }
}

extern "C" void kernel_launch(void* const* d_in, const int* in_sizes, int n_in,
                              void* d_out, int out_size, void* d_ws, size_t ws_size,
                              hipStream_t stream) {
    const float* batch   = (const float*)d_in[0];
    const float* proxies = (const float*)d_in[1];
    const int*   labels  = (const int*)d_in[2];
    float* out = (float*)d_out;

    char* ws = (char*)d_ws;
    unsigned short* A     = (unsigned short*)ws;                 //   262,144 B
    float* d_pos          = (float*)(ws + 262144);               //     4,096 B
    float* rowsum         = (float*)(ws + 266240);               //    65,536 B
    unsigned short* Pfrag = (unsigned short*)(ws + 331776);      // 25,624,576 B (1KB-aligned)

    prep_kernel<<<128 + NPB, 256, 0, stream>>>(batch, proxies, labels, A, Pfrag, d_pos, rowsum, out);
    main_kernel<<<NPB, 256, 0, stream>>>(A, Pfrag, rowsum);
    final_kernel<<<4, 256, 0, stream>>>(rowsum, d_pos, out);
}

// Round 10
// 125.184 us; speedup vs baseline: 1.1561x; 1.1561x over previous
//
#include <hip/hip_runtime.h>
#include <hip/hip_bf16.h>
#include <math.h>

#define BS 1024
#define D 128
#define NP 100000
#define PROWS 100096              // padded to multiple of 64 (96 zero rows)
#define NPG 1564                  // 64-proxy groups (= main grid)
#define NSLICE 16                 // rowsum slices (atomic contention / 16)
#define LOG2E 1.44269504088896340736f

typedef float f32x4 __attribute__((ext_vector_type(4)));
typedef float f32x16 __attribute__((ext_vector_type(16)));
typedef __bf16 bf16x8 __attribute__((ext_vector_type(8)));
typedef unsigned short u16x8 __attribute__((ext_vector_type(8)));

#if defined(__has_builtin)
#if __has_builtin(__builtin_amdgcn_exp2f)
#define FAST_EXP2(x) __builtin_amdgcn_exp2f(x)
#endif
#endif
#ifndef FAST_EXP2
#define FAST_EXP2(x) exp2f(x)
#endif

static __device__ __forceinline__ unsigned short f2bf(float x) {
    unsigned int u = __float_as_uint(x);
    return (unsigned short)((u + 0x7fffu + ((u >> 16) & 1u)) >> 16);  // RNE
}

// ---------- kernel 1: batch -> bf16 Abat (FRAGMENT-READY), d_pos ----------
// (round-6 prep, unchanged: 128 blocks, ~5us. Pfrag prep branch DELETED --
// round 9 measured it at ~+25-30us, more than it saved in main.)
// Fragment-ready layout (validated rounds 3-9, absmax 0.0):
// element (row,k) at byte
//   ((row>>5)*8 + (k>>4))*1024 + ((k>>3)&1)*512 + (row&31)*16 + (k&7)*2
__global__ __launch_bounds__(256) void prep_kernel(
    const float* __restrict__ batch, const float* __restrict__ proxies,
    const int* __restrict__ labels, unsigned short* __restrict__ Abat,
    float* __restrict__ d_pos, float* __restrict__ rowsum,
    float* __restrict__ out)
{
    // zero the 16x1024 rowsum slices (128 blocks x 128 entries)
    if (threadIdx.x < 128) rowsum[blockIdx.x * 128 + threadIdx.x] = 0.f;
    if (blockIdx.x == 0 && threadIdx.x == 0) out[0] = 0.f;

    int wave = threadIdx.x >> 6, lane = threadIdx.x & 63;
    int sub = lane >> 5, c = lane & 31;
    int row = blockIdx.x * 8 + wave * 2 + sub;   // 0..1023 (batch col)
    float4 v = *(const float4*)(batch + (size_t)row * D + c * 4);
    float ss = v.x*v.x + v.y*v.y + v.z*v.z + v.w*v.w;
    #pragma unroll
    for (int m = 1; m < 32; m <<= 1) ss += __shfl_xor(ss, m, 64);
    float sc = 3.0f / fmaxf(sqrtf(ss), 1e-12f);
    ushort4 pk;
    pk.x = f2bf(v.x*sc); pk.y = f2bf(v.y*sc);
    pk.z = f2bf(v.z*sc); pk.w = f2bf(v.w*sc);
    {
        int col_blk = row >> 5, lr = row & 31;
        int s = c >> 2, h2 = (c >> 1) & 1, j0 = (c & 1) * 4;
        size_t off = (((size_t)(col_blk * 8 + s) * 2 + h2) << 9) + lr * 16 + j0 * 2;
        *(ushort4*)((char*)Abat + off) = pk;
    }
    int lab = labels[row];
    float4 p4 = *(const float4*)(proxies + (size_t)lab * D + c * 4);
    float ps = p4.x*p4.x + p4.y*p4.y + p4.z*p4.z + p4.w*p4.w;
    #pragma unroll
    for (int m = 1; m < 32; m <<= 1) ps += __shfl_xor(ps, m, 64);
    float psc = 3.0f / fmaxf(sqrtf(ps), 1e-12f);
    float dt = (v.x*sc)*(p4.x*psc) + (v.y*sc)*(p4.y*psc)
             + (v.z*sc)*(p4.z*psc) + (v.w*sc)*(p4.w*psc);
    #pragma unroll
    for (int m = 1; m < 32; m <<= 1) dt += __shfl_xor(dt, m, 64);
    if (c == 0) d_pos[row] = 18.0f - 2.0f * dt;
}

// ---------- kernel 2: streaming GEMM + exp row-sums -----------------------
// Synthesis of rounds 6+9: block = ONE 64-proxy group (1564 blocks, 6256
// waves = 24.4/CU supply, 2x round 9). Stage only 16KB fp32 -> norm ->
// bf16 fragment-layout LDS (1/4 of round-6 staging), one barrier; all 4
// waves load the SAME Af[2][8] (AGPR-placed, round-9 evidence: VGPR=56),
// then each streams a different 256-col batch quarter with DOUBLE-BUFFERED
// coalesced Bf loads (statically-named Bf0/Bf1, manual 2-unroll -- runtime
// indexing would go to scratch). No Pfrag kernel, no fp32 re-read in loop.
// Budget: VGPR side Bf0+Bf1(64)+misc~30 <= 128; AGPR side Af(64)+acc(32).
// __launch_bounds__ law (rounds 1/2/4/5): arg=2 only. NEVER arg=4.
__global__ __launch_bounds__(256, 2) void main_kernel(
    const float* __restrict__ proxies,
    const unsigned short* __restrict__ Abat,   // batch, fragment-ready
    float* __restrict__ rowsum)                // [NSLICE][BS]
{
    __shared__ char Plds[64 * D * 2];          // 16 KB, fragment layout
    const int tid = threadIdx.x;
    const int lane = tid & 63;
    const int wave = tid >> 6;                 // 0..3 = batch quarter
    const int l31 = lane & 31, hi = lane >> 5;
    const int pg = blockIdx.x;                 // 64-proxy group

    // ---- staging: p = tid>>2 (0..63), q = tid&3 (32 floats each) ---------
    {
        int p = tid >> 2, q = tid & 3;
        int pidx = pg * 64 + p;
        const float* src = proxies + (size_t)pidx * D + q * 32;
        float ss = 0.f;
        if (pidx < NP) {
            #pragma unroll
            for (int j = 0; j < 8; ++j) {
                float4 v = *(const float4*)(src + j * 4);
                ss += v.x*v.x + v.y*v.y + v.z*v.z + v.w*v.w;
            }
        }
        ss += __shfl_xor(ss, 1, 64);             // combine 4 quarters
        ss += __shfl_xor(ss, 2, 64);
        float sc = 3.0f / fmaxf(sqrtf(ss), 1e-12f);
        #pragma unroll
        for (int i2 = 0; i2 < 4; ++i2) {
            u16x8 w = (u16x8){0,0,0,0,0,0,0,0};
            if (pidx < NP) {
                float4 a = *(const float4*)(src + i2 * 8);      // L1 hit
                float4 b = *(const float4*)(src + i2 * 8 + 4);
                w[0] = f2bf(a.x*sc); w[1] = f2bf(a.y*sc);
                w[2] = f2bf(a.z*sc); w[3] = f2bf(a.w*sc);
                w[4] = f2bf(b.x*sc); w[5] = f2bf(b.y*sc);
                w[6] = f2bf(b.z*sc); w[7] = f2bf(b.w*sc);
            }
            int cl = q * 4 + i2;                 // 16B k-chunk index
            size_t off = ((size_t)((p >> 5) * 8 + (cl >> 1)) << 10)
                       + ((size_t)(cl & 1) << 9) + (p & 31) * 16;
            *(u16x8*)(Plds + off) = w;
        }
    }
    __syncthreads();

    // ---- Af cache: 64 proxies x K=128, 16 ds_read_b128, AGPR-resident ----
    bf16x8 Af[2][8];
    #pragma unroll
    for (int t = 0; t < 2; ++t) {
        #pragma unroll
        for (int s = 0; s < 8; ++s)
            Af[t][s] = *(const bf16x8*)(Plds + (((t << 3) | s) << 10) + lane * 16);
    }

    const float c1 = 2.0f * LOG2E, c0 = -18.0f * LOG2E;
    float* rs_base = rowsum + (size_t)(pg & (NSLICE - 1)) * BS;

    auto loadB = [&](bf16x8 (&Bf)[8], int cb) {
        const char* bp = (const char*)Abat + ((size_t)cb << 13) + lane * 16;
        #pragma unroll
        for (int s = 0; s < 8; ++s)
            Bf[s] = *(const bf16x8*)(bp + ((size_t)s << 10));
    };
    auto do_cb = [&](const bf16x8 (&Bf)[8], int cb) {
        f32x16 a0 = {0.f,0.f,0.f,0.f,0.f,0.f,0.f,0.f,
                     0.f,0.f,0.f,0.f,0.f,0.f,0.f,0.f};
        f32x16 a1 = a0;
        #pragma unroll
        for (int s = 0; s < 8; ++s) {
            a0 = __builtin_amdgcn_mfma_f32_32x32x16_bf16(Af[0][s], Bf[s], a0, 0, 0, 0);
            a1 = __builtin_amdgcn_mfma_f32_32x32x16_bf16(Af[1][s], Bf[s], a1, 0, 0, 0);
        }
        float e0 = 0.f, e1 = 0.f, e2 = 0.f, e3 = 0.f;
        #pragma unroll
        for (int r = 0; r < 4; ++r) {
            e0 += FAST_EXP2(fmaf(a0[4*r+0], c1, c0));
            e1 += FAST_EXP2(fmaf(a0[4*r+1], c1, c0));
            e2 += FAST_EXP2(fmaf(a0[4*r+2], c1, c0));
            e3 += FAST_EXP2(fmaf(a0[4*r+3], c1, c0));
            e0 += FAST_EXP2(fmaf(a1[4*r+0], c1, c0));
            e1 += FAST_EXP2(fmaf(a1[4*r+1], c1, c0));
            e2 += FAST_EXP2(fmaf(a1[4*r+2], c1, c0));
            e3 += FAST_EXP2(fmaf(a1[4*r+3], c1, c0));
        }
        float rs = (e0 + e1) + (e2 + e3);
        rs += __shfl_xor(rs, 32, 64);            // combine the two row-halves
        if (hi == 0)
            atomicAdd(rs_base + cb * 32 + l31, rs);
    };

    // ---- 8 col-blocks (this wave's 256 batch cols), Bf double-buffered ---
    bf16x8 Bf0[8], Bf1[8];
    const int cb0 = wave * 8;
    loadB(Bf0, cb0);
    #pragma unroll 1
    for (int j = 0; j < 4; ++j) {
        loadB(Bf1, cb0 + 2 * j + 1);     // prefetch flies under do_cb's MFMAs
        do_cb(Bf0, cb0 + 2 * j);
        if (j < 3) loadB(Bf0, cb0 + 2 * j + 2);
        do_cb(Bf1, cb0 + 2 * j + 1);
    }
}

// ---------- kernel 3: final lse + mean (4 blocks, atomicAdd out) ----------
__global__ __launch_bounds__(256) void final_kernel(
    const float* __restrict__ rowsum, const float* __restrict__ d_pos,
    float* __restrict__ out)
{
    int row = blockIdx.x * 256 + threadIdx.x;
    float tot = 0.f;
    #pragma unroll
    for (int s = 0; s < NSLICE; ++s)
        tot += rowsum[(size_t)s * BS + row];
    float dp = d_pos[row];
    const float PADC = 96.0f * exp2f(-18.0f * LOG2E);  // zero-pad rows
    float neg = tot - expf(-dp) - PADC;                // drop own column
    float val = dp + logf(fmaxf(neg, 1e-37f));
    #pragma unroll
    for (int m = 1; m < 64; m <<= 1) val += __shfl_xor(val, m, 64);
    __shared__ float red[4];
    if ((threadIdx.x & 63) == 0) red[threadIdx.x >> 6] = val;
    __syncthreads();
    if (threadIdx.x == 0) {
        float v = (red[0] + red[1]) + (red[2] + red[3]);
        atomicAdd(out, v * (1.0f / 1024.0f));
    }
}

extern "C" void kernel_launch(void* const* d_in, const int* in_sizes, int n_in,
                              void* d_out, int out_size, void* d_ws, size_t ws_size,
                              hipStream_t stream) {
    const float* batch   = (const float*)d_in[0];
    const float* proxies = (const float*)d_in[1];
    const int*   labels  = (const int*)d_in[2];
    float* out = (float*)d_out;

    char* ws = (char*)d_ws;
    unsigned short* A  = (unsigned short*)ws;                    //   262,144 B
    float* d_pos       = (float*)(ws + 262144);                  //     4,096 B
    float* rowsum      = (float*)(ws + 266240);                  //    65,536 B

    prep_kernel<<<128, 256, 0, stream>>>(batch, proxies, labels, A, d_pos, rowsum, out);
    main_kernel<<<NPG, 256, 0, stream>>>(proxies, A, rowsum);
    final_kernel<<<4, 256, 0, stream>>>(rowsum, d_pos, out);
}